// Round 4
// baseline (323.144 us; speedup 1.0000x reference)
//
#include <hip/hip_runtime.h>

// Problem constants (from reference):
//   D = 8388608 elements, N = M = 1024 (power of two -> mod == AND)
// Outputs concatenated in d_out (float32):
//   [0,      D)      phase_out  (as float)
//   [D,     2D)      mag_out    (as float)
//   [2D,    3D)      signal
//   [3D]             strength   (scalar)
//   [3D+1,  4D+1)    grad_phase
//   [4D+1,  5D+1)    grad_mag
//
// Two-kernel design (r2's fused atomic tail regressed 5x — never again).
// r4 change: ALL stores 32B-aligned. Grad sections are +1-float offset, so
// each thread stores the window [G+base, G+base+8) = grad elements
// base-1..base+6; the -1 element comes from the previous thread via LDS.
// Seams: addr 3D is the strength slot (dummy here, overwritten by the
// reduce kernel afterwards on the same stream); addr 4D = grad_phase[D-1]
// and addr 5D = grad_mag[D-1] are written by block 0 / tid 0, which
// recomputes element D-1 from 4 scalar idx loads.
constexpr int D_TOTAL = 8388608;
constexpr int TBL = 1024;
constexpr int IDX_MASK = 1023;
constexpr int BLOCK = 256;
constexpr int VEC = 8;                        // elements per thread
constexpr int ELEMS_PER_BLOCK = BLOCK * VEC;  // 2048
constexpr int NBLOCKS = D_TOTAL / ELEMS_PER_BLOCK;  // 4096

typedef float f32x8 __attribute__((ext_vector_type(8)));
typedef int   i32x8 __attribute__((ext_vector_type(8)));

__global__ __launch_bounds__(BLOCK) void phasecell_main(
    const int* __restrict__ ctx_p, const int* __restrict__ ctx_m,
    const int* __restrict__ self_p, const int* __restrict__ self_m,
    const float* __restrict__ cos_t, const float* __restrict__ exp_t,
    const float* __restrict__ dcos_t, const float* __restrict__ dexp_t,
    float* __restrict__ out, float* __restrict__ block_sums) {
  // Stage interleaved tables in LDS: one ds_read_b64 per gather.
  // (r2 measured ~5 conflict-cycles/gather -> ~4us total. Not a bottleneck.)
  __shared__ float2 s_phase[TBL];  // (cos, dcos)
  __shared__ float2 s_mag[TBL];    // (exp, dexp)
  const int tid = threadIdx.x;
  for (int i = tid; i < TBL; i += BLOCK) {
    s_phase[i] = make_float2(cos_t[i], dcos_t[i]);
    s_mag[i]   = make_float2(exp_t[i], dexp_t[i]);
  }
  __syncthreads();

  const int base = (blockIdx.x * BLOCK + tid) * VEC;

  const i32x8 cp = *reinterpret_cast<const i32x8*>(ctx_p + base);
  const i32x8 cm = *reinterpret_cast<const i32x8*>(ctx_m + base);
  const i32x8 sp = *reinterpret_cast<const i32x8*>(self_p + base);
  const i32x8 sm = *reinterpret_cast<const i32x8*>(self_m + base);

  int p[VEC], m[VEC];
#pragma unroll
  for (int j = 0; j < VEC; ++j) {
    p[j] = (cp[j] + sp[j]) & IDX_MASK;
    m[j] = (cm[j] + sm[j]) & IDX_MASK;
  }

  f32x8 po, mo, sig;
  float gph[VEC], gmg[VEC];
  float local = 0.f;
#pragma unroll
  for (int j = 0; j < VEC; ++j) {
    const float2 ph = s_phase[p[j]];
    const float2 mg = s_mag[m[j]];
    const float s = ph.x * mg.x;
    sig[j] = s;
    gph[j] = ph.y * mg.x;
    gmg[j] = ph.x * mg.y;
    po[j] = (float)p[j];
    mo[j] = (float)m[j];
    local += s;
  }

  // 32B-aligned nontemporal stores (zero reuse; keep inputs warm in L2/L3).
  __builtin_nontemporal_store(po,  (f32x8*)(out + base));
  __builtin_nontemporal_store(mo,  (f32x8*)(out + D_TOTAL + base));
  __builtin_nontemporal_store(sig, (f32x8*)(out + 2 * D_TOTAL + base));

  // Hand the last grad pair to the next thread (shift-by-one window).
  __shared__ float2 s_lastg[BLOCK];
  s_lastg[tid] = make_float2(gph[VEC - 1], gmg[VEC - 1]);
  __syncthreads();

  float pgp, pgm;  // grad values for element base-1 (window slot 0)
  if (tid > 0) {
    const float2 t = s_lastg[tid - 1];
    pgp = t.x;
    pgm = t.y;
  } else if (blockIdx.x > 0) {
    const int e = blockIdx.x * ELEMS_PER_BLOCK - 1;  // prev block's last elem
    const int pp = (ctx_p[e] + self_p[e]) & IDX_MASK;
    const int mm = (ctx_m[e] + self_m[e]) & IDX_MASK;
    pgp = s_phase[pp].y * s_mag[mm].x;
    pgm = s_phase[pp].x * s_mag[mm].y;
  } else {
    // Block 0, tid 0: window slot 0 of the phase stream is addr 3D (the
    // strength slot -> dummy, reduce kernel overwrites it); slot 0 of the
    // mag stream is addr 4D == grad_phase[D-1]. Also write the final
    // element grad_mag[D-1] at addr 5D. Element D-1 recomputed here.
    const int e = D_TOTAL - 1;
    const int pp = (ctx_p[e] + self_p[e]) & IDX_MASK;
    const int mm = (ctx_m[e] + self_m[e]) & IDX_MASK;
    const float gpL = s_phase[pp].y * s_mag[mm].x;
    const float gmL = s_phase[pp].x * s_mag[mm].y;
    pgp = 0.0f;   // placeholder; out[3D] = strength written by reduce kernel
    pgm = gpL;    // addr 4D holds grad_phase[D-1]
    out[5 * (size_t)D_TOTAL] = gmL;  // last output element
  }

  f32x8 wph, wmg;
  wph[0] = pgp;
  wmg[0] = pgm;
#pragma unroll
  for (int k = 1; k < VEC; ++k) {
    wph[k] = gph[k - 1];
    wmg[k] = gmg[k - 1];
  }
  __builtin_nontemporal_store(wph, (f32x8*)(out + 3 * D_TOTAL + base));
  __builtin_nontemporal_store(wmg, (f32x8*)(out + 4 * D_TOTAL + base));

  // Block reduction of `local` -> block_sums[blockIdx.x] (deterministic).
#pragma unroll
  for (int off = 32; off > 0; off >>= 1) local += __shfl_down(local, off, 64);
  __shared__ float wsum[BLOCK / 64];
  const int wave = tid >> 6;
  const int lane = tid & 63;
  if (lane == 0) wsum[wave] = local;
  __syncthreads();
  if (tid == 0) {
    float t = 0.f;
#pragma unroll
    for (int w = 0; w < BLOCK / 64; ++w) t += wsum[w];
    block_sums[blockIdx.x] = t;
  }
}

__global__ __launch_bounds__(BLOCK) void phasecell_reduce(
    const float* __restrict__ partials, float* __restrict__ strength_out) {
  float s = 0.f;
  for (int i = threadIdx.x; i < NBLOCKS; i += BLOCK) s += partials[i];
#pragma unroll
  for (int off = 32; off > 0; off >>= 1) s += __shfl_down(s, off, 64);
  __shared__ float wsum[BLOCK / 64];
  const int wave = threadIdx.x >> 6;
  const int lane = threadIdx.x & 63;
  if (lane == 0) wsum[wave] = s;
  __syncthreads();
  if (threadIdx.x == 0) {
    float t = 0.f;
#pragma unroll
    for (int w = 0; w < BLOCK / 64; ++w) t += wsum[w];
    strength_out[0] = t;  // out[3D]
  }
}

extern "C" void kernel_launch(void* const* d_in, const int* in_sizes, int n_in,
                              void* d_out, int out_size, void* d_ws, size_t ws_size,
                              hipStream_t stream) {
  const int* ctx_p  = (const int*)d_in[0];
  const int* ctx_m  = (const int*)d_in[1];
  const int* self_p = (const int*)d_in[2];
  const int* self_m = (const int*)d_in[3];
  const float* cos_t  = (const float*)d_in[4];
  const float* exp_t  = (const float*)d_in[5];
  const float* dcos_t = (const float*)d_in[6];
  const float* dexp_t = (const float*)d_in[7];
  float* out = (float*)d_out;
  float* block_sums = (float*)d_ws;  // NBLOCKS floats = 16 KB

  phasecell_main<<<NBLOCKS, BLOCK, 0, stream>>>(
      ctx_p, ctx_m, self_p, self_m, cos_t, exp_t, dcos_t, dexp_t, out, block_sums);
  phasecell_reduce<<<1, BLOCK, 0, stream>>>(block_sums, out + 3 * (size_t)D_TOTAL);
}